// Round 1
// baseline (131.224 us; speedup 1.0000x reference)
//
#include <hip/hip_runtime.h>

typedef unsigned short ushort_t;
typedef short s16x8 __attribute__((ext_vector_type(8)));   // bf16 frag vector (K=32 ops)
typedef short s16x4 __attribute__((ext_vector_type(4)));   // bf16 frag vector (K=16 ops)
typedef float f32x4 __attribute__((ext_vector_type(4)));

// Device pass has __builtin_amdgcn_mfma_f32_16x16x16bf16_1k (round-13 log:
// only HOST pass errored). __has_builtin can't see aux-target builtins in the
// host pass, so gate on __HIP_DEVICE_COMPILE__. The host-pass stub must be
// __device__ __host__ because the host pass semantically checks __global__
// bodies (round-14 error) — it never codegens for device.
#if defined(__HIP_DEVICE_COMPILE__)
#define MFMA16(a, b, c) __builtin_amdgcn_mfma_f32_16x16x16bf16_1k(a, b, c, 0, 0, 0)
#else
__device__ __host__ static inline f32x4 MFMA16(s16x4, s16x4, f32x4 c) { return c; }
#endif

#define DEVINL __device__ __forceinline__

DEVINL ushort_t f2b(float f) {           // fp32 -> bf16 RNE
  union { float f; unsigned int u; } v; v.f = f;
  unsigned int r = (v.u + 0x7fffu + ((v.u >> 16) & 1u)) >> 16;
  return (ushort_t)r;
}

DEVINL ushort_t f2b_hw(float f) {        // fp32 -> bf16 via HW v_cvt (RNE)
  union { __bf16 h; ushort_t u; } cv;
  cv.h = (__bf16)f;
  return cv.u;
}

// ---------- prep: fused {Wqkv transpose, Wout transpose, fold} ----------
__global__ __launch_bounds__(256) void prep_kernel(
    const float* __restrict__ Wqkv, const float* __restrict__ bq,
    const float* __restrict__ Wod, const float* __restrict__ bod,
    const float* __restrict__ Wout,
    ushort_t* __restrict__ WqkvT, ushort_t* __restrict__ WoT,
    float* __restrict__ Wcomb, float* __restrict__ bcomb)
{
  __shared__ ushort_t tile[64 * 72];
  const int b = blockIdx.x;
  const int tid = threadIdx.x;

  if (b < 256) {
    const float* in;
    ushort_t* out;
    int N, bx, by;
    if (b < 192) { in = Wqkv; out = WqkvT; N = 1536; bx = b % 24; by = b / 24; }
    else         { in = Wout; out = WoT;   N = 512;  bx = (b - 192) % 8; by = (b - 192) / 8; }
    const int K = 512;
    const int n0 = bx * 64, k0 = by * 64;
    const int cr = tid >> 4;
    const int cc = (tid & 15) * 4;
#pragma unroll
    for (int p = 0; p < 4; p++) {
      int k = k0 + p * 16 + cr;
      float4 v = *(const float4*)(in + k * N + n0 + cc);
      ushort4 o; o.x = f2b(v.x); o.y = f2b(v.y); o.z = f2b(v.z); o.w = f2b(v.w);
      *(ushort4*)(tile + (p * 16 + cr) * 72 + cc) = o;
    }
    __syncthreads();
#pragma unroll
    for (int p = 0; p < 4; p++) {
      int n = n0 + p * 16 + cr;
      ushort4 v;
      v.x = tile[(cc + 0) * 72 + p * 16 + cr];
      v.y = tile[(cc + 1) * 72 + p * 16 + cr];
      v.z = tile[(cc + 2) * 72 + p * 16 + cr];
      v.w = tile[(cc + 3) * 72 + p * 16 + cr];
      *(ushort4*)(out + n * K + k0 + cc) = v;
    }
    return;
  }

  // fold: one wave per c-row
  const int w = tid >> 6, lane = tid & 63;
  const int c = (b - 256) * 4 + w;
  if (c > 512) return;
  float a[8];
  const float* src = (c < 512) ? (Wqkv + c * 1536 + lane * 8) : (bq + lane * 8);
  float4 a0 = *(const float4*)(src);
  float4 a1 = *(const float4*)(src + 4);
  a[0]=a0.x; a[1]=a0.y; a[2]=a0.z; a[3]=a0.w;
  a[4]=a1.x; a[5]=a1.y; a[6]=a1.z; a[7]=a1.w;

  float s[16];
#pragma unroll
  for (int j = 0; j < 16; j++) s[j] = 0.f;
#pragma unroll
  for (int i = 0; i < 8; i++) {
    const float* wp = Wod + (lane * 8 + i) * 16;
#pragma unroll
    for (int j = 0; j < 16; j++) s[j] += a[i] * wp[j];
  }
#pragma unroll
  for (int mask = 1; mask < 64; mask <<= 1)
#pragma unroll
    for (int j = 0; j < 16; j++) s[j] += __shfl_xor(s[j], mask);

  if (lane < 16) {
    if (c < 512) Wcomb[c * 16 + lane] = s[lane];
    else         bcomb[lane] = s[lane] + bod[lane];
  }
}

// ------- merged qkv GEMM + od: blocks [0,384) gemm, [384,896) od -------
__global__ __launch_bounds__(256) void qkv_od_kernel(
    const float* __restrict__ x, const ushort_t* __restrict__ WT,
    const float* __restrict__ bqkv,
    const float* __restrict__ Wcomb, const float* __restrict__ bcomb,
    const int* __restrict__ lenp,
    ushort_t* __restrict__ Qh, ushort_t* __restrict__ Kh, ushort_t* __restrict__ VT,
    float* __restrict__ params)
{
  const int blk = blockIdx.x;
  const int tid = threadIdx.x;

  if (blk >= 384) {
    // ---- od path ----
    const int w = tid >> 6, lane = tid & 63;
    const int m = (blk - 384) * 4 + w;   // 0..2047
    int li = lenp[0];
    float len = (li > 0 && li < 1048576) ? (float)li : 1024.0f;

    const float* qp = x + m * 512 + lane * 8;
    float q[8];
    float4 qa = *(const float4*)(qp);
    float4 qb = *(const float4*)(qp + 4);
    q[0]=qa.x; q[1]=qa.y; q[2]=qa.z; q[3]=qa.w;
    q[4]=qb.x; q[5]=qb.y; q[6]=qb.z; q[7]=qb.w;

    float s[16];
#pragma unroll
    for (int j = 0; j < 16; j++) s[j] = 0.f;
#pragma unroll
    for (int i = 0; i < 8; i++) {
      const float* wp = Wcomb + (lane * 8 + i) * 16;
#pragma unroll
      for (int j = 0; j < 16; j++) s[j] += q[i] * wp[j];
    }
#pragma unroll
    for (int mask = 1; mask < 64; mask <<= 1)
#pragma unroll
      for (int j = 0; j < 16; j++) s[j] += __shfl_xor(s[j], mask);

    if (lane < 8) {
      int h = lane;
      int bb = m >> 10, t = m & 1023;
      float odo = s[h] + bcomb[h];
      float odd = s[8 + h] + bcomb[8 + h];
      float offset = tanhf(odo) * len;
      float dur = len / (1.f + expf(-odd));
      float anchor = (float)t + offset;
      float start = anchor - dur, end = anchor + dur;
      float bl = floorf(start), br = ceilf(end);
      float al = floorf(anchor);
      float da = anchor - al;
      float* pp = params + ((bb * 8 + h) * 1024 + t) * 6;
      pp[0] = bl; pp[1] = br; pp[2] = al;
      pp[3] = bl - start; pp[4] = end - br; pp[5] = da;
    }
    return;
  }

  // ---- qkv gemm path ----
  __shared__ ushort_t As[64 * 32];
  __shared__ ushort_t Bs[128 * 32];
  const int lane = tid & 63, w = tid >> 6;
  const int wr = w >> 1, wc = w & 1;          // wave tile 32x64
  const int quad = lane >> 4, l16 = lane & 15;
  const int bx = blk % 12, by = blk / 12;
  const int m0 = by * 64, n0 = bx * 128;

  f32x4 acc[2][4];
#pragma unroll
  for (int i = 0; i < 2; i++)
#pragma unroll
    for (int j = 0; j < 4; j++) acc[i][j] = f32x4{0.f, 0.f, 0.f, 0.f};

  const int idx = tid * 8;
  const int ra = idx >> 5, ca = idx & 31;
  const int rb1 = (idx + 2048) >> 5, cb1 = (idx + 2048) & 31;

  for (int k0 = 0; k0 < 512; k0 += 32) {
    const float* xa = x + (m0 + ra) * 512 + k0 + ca;
    float4 x0 = *(const float4*)(xa);
    float4 x1 = *(const float4*)(xa + 4);
    s16x8 vb0 = *(const s16x8*)(WT + (n0 + ra) * 512 + k0 + ca);
    s16x8 vb1 = *(const s16x8*)(WT + (n0 + rb1) * 512 + k0 + cb1);
    s16x8 va;
    va[0] = (short)f2b_hw(x0.x); va[1] = (short)f2b_hw(x0.y);
    va[2] = (short)f2b_hw(x0.z); va[3] = (short)f2b_hw(x0.w);
    va[4] = (short)f2b_hw(x1.x); va[5] = (short)f2b_hw(x1.y);
    va[6] = (short)f2b_hw(x1.z); va[7] = (short)f2b_hw(x1.w);
    __syncthreads();
    *(s16x8*)(As + idx) = va;
    *(s16x8*)(Bs + idx) = vb0;
    *(s16x8*)(Bs + idx + 2048) = vb1;
    __syncthreads();

    s16x8 af[2], bfr[4];
#pragma unroll
    for (int mt = 0; mt < 2; mt++)
      af[mt] = *(const s16x8*)(As + (wr * 32 + mt * 16 + l16) * 32 + quad * 8);
#pragma unroll
    for (int nt = 0; nt < 4; nt++)
      bfr[nt] = *(const s16x8*)(Bs + (wc * 64 + nt * 16 + l16) * 32 + quad * 8);
#pragma unroll
    for (int mt = 0; mt < 2; mt++)
#pragma unroll
      for (int nt = 0; nt < 4; nt++)
        acc[mt][nt] = __builtin_amdgcn_mfma_f32_16x16x32_bf16(af[mt], bfr[nt], acc[mt][nt], 0, 0, 0);
  }

#pragma unroll
  for (int nt = 0; nt < 4; nt++) {
    int c = n0 + wc * 64 + nt * 16 + l16;
    float bias = bqkv[c];
    int which = c >> 9;
    int e = c & 511;
    int h = e >> 6, d = e & 63;
#pragma unroll
    for (int mt = 0; mt < 2; mt++) {
      int mbase = m0 + wr * 32 + mt * 16 + quad * 4;
      int bb = mbase >> 10, t = mbase & 1023;
      int bh = bb * 8 + h;
      if (which == 2) {
        ushort4 pk;
        pk.x = f2b(acc[mt][nt][0] + bias);
        pk.y = f2b(acc[mt][nt][1] + bias);
        pk.z = f2b(acc[mt][nt][2] + bias);
        pk.w = f2b(acc[mt][nt][3] + bias);
        *(ushort4*)(VT + (bh * 64 + d) * 1024 + t) = pk;
      } else {
        ushort_t* dst = (which == 0) ? Qh : Kh;
        float sc = (which == 0) ? 0.125f : 1.0f;
#pragma unroll
        for (int rr = 0; rr < 4; rr++)
          dst[(bh * 1024 + t + rr) * 64 + d] = f2b((acc[mt][nt][rr] + bias) * sc);
      }
    }
  }
}

// ------- attention v4: band-parallel 512-thread blocks -------
// Two wave-groups per block: group wg processes tiles tlo+2i+wg (even/odd
// interleave), each with its own single-buffered K/V LDS tile (the v3
// ping-pong buffers become group 1's buffers — total LDS unchanged 36.9 KB).
// Per-block serial tile chain halves (13 -> ~7) and resident waves/CU go
// 16 -> 24-32 (launch_bounds(512,6)), attacking the latency-bound regime.
// In-block merge extends 4 -> 8 partials (overlay 33.8 KB fits).
__global__ __launch_bounds__(512, 6) void attn_kernel(
    const ushort_t* __restrict__ Qh, const ushort_t* __restrict__ Kh,
    const ushort_t* __restrict__ VT, const float* __restrict__ params,
    ushort_t* __restrict__ Oh)
{
  constexpr int TS = 64 * 72;                   // one K or V tile (elems)
  __shared__ __align__(16) ushort_t KV[4 * TS]; // [wg][K|V]; merge overlay after loop

  const int tid = threadIdx.x;
  const int wg = tid >> 8;                      // tile-parity group 0/1
  const int t8 = tid & 255;
  const int lane = tid & 63;
  const int wc = t8 >> 6;                       // col-quarter within group
  const int quad = lane >> 4, l16 = lane & 15;
  const int bh = blockIdx.x;
  const int mrow = blockIdx.y * 16;

  // params per lane: row q = l16 (quads redundant by construction)
  const float* ppl = params + (bh * 1024 + mrow + l16) * 6;
  float bl = ppl[0], br = ppl[1], al = ppl[2];
  float wl = ppl[3], wr2 = ppl[4], da = ppl[5];
  bool empty = (br < 0.f) || (bl > 1023.f);
  float lo = empty ? 0.f    : fmaxf(bl, 0.f);
  float hi = empty ? 1023.f : fminf(br, 1023.f);
#pragma unroll
  for (int mask = 1; mask < 16; mask <<= 1) {
    lo = fminf(lo, __shfl_xor(lo, mask));
    hi = fmaxf(hi, __shfl_xor(hi, mask));
  }
  const int tlo = __builtin_amdgcn_readfirstlane(((int)lo) >> 6);
  const int thi = __builtin_amdgcn_readfirstlane(((int)hi) >> 6);
  const int ntile = thi - tlo + 1;
  const int iters = (ntile + 1) >> 1;

  // Q fragments (B-operand): bq[i][k=quad*4+j] = Q[q=l16][i*16+quad*4+j]
  const ushort_t* qrow = Qh + (bh * 1024 + mrow + l16) * 64;
  s16x4 bq[4];
#pragma unroll
  for (int i = 0; i < 4; i++)
    bq[i] = *(const s16x4*)(qrow + i * 16 + quad * 4);

  float lr = 0.f;
  f32x4 Oacc[4];
#pragma unroll
  for (int g = 0; g < 4; g++) Oacc[g] = f32x4{0.f, 0.f, 0.f, 0.f};

  // staging: thread -> row t8>>2 (0..63), 16-elem segment (t8&3)*16
  const int srow = t8 >> 2, sseg = (t8 & 3) * 16;
  const ushort_t* kgb = Kh + (bh * 1024 + srow) * 64 + sseg;   // + r0*64
  const ushort_t* vgb = VT + (bh * 64 + srow) * 1024 + sseg;   // + r0
  ushort_t* Kt = KV + wg * 2 * TS;
  ushort_t* Vt = Kt + TS;

  for (int i = 0; i < iters; i++) {
    const int ti = 2 * i + wg;
    const bool act = (ti < ntile);               // group 1 may idle last iter
    const int tt = tlo + ti;
    const int r0 = tt * 64;

    s16x8 kr0, kr1, vr0, vr1;
    if (act) {
      kr0 = *(const s16x8*)(kgb + r0 * 64);
      kr1 = *(const s16x8*)(kgb + r0 * 64 + 8);
      vr0 = *(const s16x8*)(vgb + r0);
      vr1 = *(const s16x8*)(vgb + r0 + 8);
    }
    __syncthreads();                             // prev iter's LDS reads done
    if (act) {
      *(s16x8*)(Kt + srow * 72 + sseg)     = kr0;
      *(s16x8*)(Kt + srow * 72 + sseg + 8) = kr1;
      *(s16x8*)(Vt + srow * 72 + sseg)     = vr0;
      *(s16x8*)(Vt + srow * 72 + sseg + 8) = vr1;
    }
    __syncthreads();                             // buffers ready
    if (!act) continue;

    // S^T = K.Q^T over this group's wave's 16 K-cols
    const ushort_t* krow = Kt + (wc * 16 + l16) * 72;
    f32x4 z = {0.f, 0.f, 0.f, 0.f};
    __builtin_amdgcn_s_setprio(1);
#pragma unroll
    for (int ii = 0; ii < 4; ii++) {
      s16x4 ak = *(const s16x4*)(krow + ii * 16 + quad * 4);
      z = MFMA16(ak, bq[ii], z);          // D[kc][q]
    }
    __builtin_amdgcn_s_setprio(0);

    // softmax: lane handles q=l16, kc = cbase + quad*4 + rr
    const int cbase = r0 + wc * 16;
    const float c0f = (float)cbase, c1f = c0f + 15.f;
    bool f = (bl < c0f) && (br > c1f) && ((al + 1.f < c0f) || (al > c1f));
    s16x4 pt;
    if (__all((int)f)) {
#pragma unroll
      for (int rr = 0; rr < 4; rr++) {
        float pv = __expf(z[rr]);
        lr += pv;
        pt[rr] = (short)f2b_hw(pv);
      }
    } else {
#pragma unroll
      for (int rr = 0; rr < 4; rr++) {
        float cf = (float)(cbase + quad * 4 + rr);
        float s = z[rr];                 // includes 0.125 via Qh pre-scale
        float wgt = 1.f;
        wgt += (cf == bl) ? wl : 0.f;
        wgt += (cf == br) ? wr2 : 0.f;
        wgt += (cf == al + 1.f) ? da : 0.f;
        wgt += (cf == al) ? (1.f - da) : 0.f;
        s *= wgt;
        s = (cf < bl || cf > br) ? -30.f : s;
        float pv = __expf(s);
        lr += pv;
        pt[rr] = (short)f2b_hw(pv);
      }
    }

    // O^T = V^T.P^T : A = V^T frag, B = pt (register P!)
    __builtin_amdgcn_s_setprio(1);
#pragma unroll
    for (int g = 0; g < 4; g++) {
      s16x4 av = *(const s16x4*)(Vt + (g * 16 + l16) * 72 + wc * 16 + quad * 4);
      Oacc[g] = MFMA16(av, pt, Oacc[g]); // D[d][q]
    }
    __builtin_amdgcn_s_setprio(0);
  }

  // row-sum: each quad covered distinct kc -> reduce across quads
  lr += __shfl_xor(lr, 16);
  lr += __shfl_xor(lr, 32);

  // merge scratch overlays dead staging LDS (barrier-separated)
  __syncthreads();
  float* Om  = (float*)KV;               // [128][65]: partial p = wg*4+wc
  float* lwf = Om + 128 * 65;            // [128]
  const int prow = (wg * 4 + wc) * 16 + l16;
#pragma unroll
  for (int g = 0; g < 4; g++)
#pragma unroll
    for (int rr = 0; rr < 4; rr++)
      Om[prow * 65 + g * 16 + quad * 4 + rr] = Oacc[g][rr];
  if (quad == 0) lwf[prow] = lr;
  __syncthreads();

  // merge 8 partials (4 col-quarters x 2 tile-parities): 16x64 / 512 thr
  const int bb = bh >> 3, h = bh & 7;
  {
    int e = tid;                          // 1024 elems, 512 threads, 2 each
#pragma unroll
    for (int it = 0; it < 2; it++, e += 512) {
      int r = e >> 6, col = e & 63;
      float lg = 0.f, o = 0.f;
#pragma unroll
      for (int p = 0; p < 8; p++) {
        lg += lwf[p * 16 + r];
        o  += Om[(p * 16 + r) * 65 + col];
      }
      int t = mrow + r;
      Oh[((bb << 10) + t) * 512 + h * 64 + col] = f2b_hw(o / lg);
    }
  }
}

// ------- out GEMM: 64x64 tiles, grid (8,32)=256 blocks -------
__global__ __launch_bounds__(256) void out_gemm_kernel(
    const ushort_t* __restrict__ Oh, const ushort_t* __restrict__ WT,
    const float* __restrict__ bout, float* __restrict__ outp)
{
  __shared__ ushort_t As[64 * 32];
  __shared__ ushort_t Bs[64 * 32];
  const int tid = threadIdx.x;
  const int lane = tid & 63, w = tid >> 6;
  const int wr = w >> 1, wc = w & 1;          // wave tile 32x32
  const int quad = lane >> 4, l16 = lane & 15;
  const int m0 = blockIdx.y * 64, n0 = blockIdx.x * 64;

  f32x4 acc[2][2];
#pragma unroll
  for (int i = 0; i < 2; i++)
#pragma unroll
    for (int j = 0; j < 2; j++) acc[i][j] = f32x4{0.f, 0.f, 0.f, 0.f};

  const int idx = tid * 8;
  const int ra = idx >> 5, ca = idx & 31;

  for (int k0 = 0; k0 < 512; k0 += 32) {
    s16x8 va = *(const s16x8*)(Oh + (m0 + ra) * 512 + k0 + ca);
    s16x8 vb = *(const s16x8*)(WT + (n0 + ra) * 512 + k0 + ca);
    __syncthreads();
    *(s16x8*)(As + idx) = va;
    *(s16x8*)(Bs + idx) = vb;
    __syncthreads();

    s16x8 af[2], bfr[2];
#pragma unroll
    for (int mt = 0; mt < 2; mt++)
      af[mt] = *(const s16x8*)(As + (wr * 32 + mt * 16 + l16) * 32 + quad * 8);
#pragma unroll
    for (int nt = 0; nt < 2; nt++)
      bfr[nt] = *(const s16x8*)(Bs + (wc * 32 + nt * 16 + l16) * 32 + quad * 8);
#pragma unroll
    for (int mt = 0; mt < 2; mt++)
#pragma unroll
      for (int nt = 0; nt < 2; nt++)
        acc[mt][nt] = __builtin_amdgcn_mfma_f32_16x16x32_bf16(af[mt], bfr[nt], acc[mt][nt], 0, 0, 0);
  }

#pragma unroll
  for (int nt = 0; nt < 2; nt++) {
    int c = n0 + wc * 32 + nt * 16 + l16;
    float bias = bout[c];
#pragma unroll
    for (int mt = 0; mt < 2; mt++) {
#pragma unroll
      for (int rr = 0; rr < 4; rr++) {
        int m = m0 + wr * 32 + mt * 16 + quad * 4 + rr;
        outp[m * 512 + c] = acc[mt][nt][rr] + bias;
      }
    }
  }
}

extern "C" void kernel_launch(void* const* d_in, const int* in_sizes, int n_in,
                              void* d_out, int out_size, void* d_ws, size_t ws_size,
                              hipStream_t stream)
{
  const float* x    = (const float*)d_in[0];
  const float* Wqkv = (const float*)d_in[1];
  const float* bqkv = (const float*)d_in[2];
  const float* Wod  = (const float*)d_in[3];
  const float* bod  = (const float*)d_in[4];
  const float* Wout = (const float*)d_in[5];
  const float* bout = (const float*)d_in[6];
  const int* lenp   = (const int*)d_in[7];

  char* ws = (char*)d_ws;
  ushort_t* WqkvT  = (ushort_t*)(ws);                  // 1536x512 bf16
  ushort_t* WoT    = (ushort_t*)(ws + 1572864);        // 512x512 bf16
  ushort_t* Qh     = (ushort_t*)(ws + 4194304);        // 16x1024x64 bf16 (pre-scaled 0.125)
  ushort_t* Kh     = (ushort_t*)(ws + 6291456);        // 16x1024x64 bf16
  ushort_t* VT     = (ushort_t*)(ws + 8388608);        // 16x64x1024 bf16
  ushort_t* Oh     = (ushort_t*)(ws + 10485760);       // 2048x512 bf16
  float*    Wcomb  = (float*)(ws + 12582912);          // 512x16 f32
  float*    bcomb  = (float*)(ws + 12615680);          // 16 f32
  float*    params = (float*)(ws + 12615744);          // 16x1024x6 f32

  prep_kernel<<<385, 256, 0, stream>>>(Wqkv, bqkv, Wod, bod, Wout, WqkvT, WoT, Wcomb, bcomb);
  qkv_od_kernel<<<896, 256, 0, stream>>>(x, WqkvT, bqkv, Wcomb, bcomb, lenp,
                                         Qh, Kh, VT, params);
  attn_kernel<<<dim3(16, 64), 512, 0, stream>>>(Qh, Kh, VT, params, Oh);
  out_gemm_kernel<<<dim3(8, 32), 256, 0, stream>>>(Oh, WoT, bout, (float*)d_out);
}